// Round 14
// baseline (3066.447 us; speedup 1.0000x reference)
//
#include <hip/hip_runtime.h>
#include <math.h>

#define S_LEN 2048
#define BATCH 64
#define IN_D  128
#define HID   256
#define G4    1024   // 4*HID

#if defined(__has_builtin)
# if __has_builtin(__builtin_amdgcn_sdot4)
#  define USE_SDOT4 1
# endif
#endif

__device__ __forceinline__ int dot4i8(int a, int b, int c) {
#ifdef USE_SDOT4
    return __builtin_amdgcn_sdot4(a, b, c, false);
#else
    int r = c;
    r += ((a << 24) >> 24) * ((b << 24) >> 24);
    r += ((a << 16) >> 24) * ((b << 16) >> 24);
    r += ((a <<  8) >> 24) * ((b <<  8) >> 24);
    r += ( a        >> 24) * ( b        >> 24);
    return r;
#endif
}

// fake_quant value: clip(round_half_even(x*16), -128, 127)/16 — exact f32 ops
__device__ __forceinline__ float fq4(float x) {
    return fminf(fmaxf(rintf(x * 16.0f), -128.0f), 127.0f) * 0.0625f;
}

// ---------------------------------------------------------------------------
// XLA-CPU JIT-emitted exp f32 (llvm_ir_runtime VF32Exp, compiled on an FMA
// host with fast-math contract ON):
//   clamp [-88.3762626647949, 88.3762626647950]
//   fx = floor(fma(x, log2e, 0.5))               [fmuladd -> vfmadd]
//   x  = fnmadd(0.693359375, fx, x)              [mul+sub CONTRACTED]
//   x  = fnmadd(-2.12194440e-4, fx, x)           [mul+sub CONTRACTED]
//   y  = FMA Horner p0..p5; y = fma(y, x^2, x); y += 1
//   scale by 2^fx via exponent bits
// ---------------------------------------------------------------------------
__device__ __forceinline__ float exp_vsl(float x) {
    const float xc = fminf(fmaxf(x, -88.3762626647949f), 88.3762626647950f);
    const float fx = floorf(fmaf(xc, 1.44269504088896341f, 0.5f));
    float r = fmaf(-fx, 0.693359375f, xc);
    r = fmaf(fx, 2.12194440e-4f, r);
    const float z = __fmul_rn(r, r);
    float y = fmaf(r, 1.9875691500e-4f, 1.3981999507e-3f);
    y = fmaf(y, r, 8.3334519073e-3f);
    y = fmaf(y, r, 4.1665795894e-2f);
    y = fmaf(y, r, 1.6666665459e-1f);
    y = fmaf(y, r, 5.0000001201e-1f);
    y = fmaf(y, z, r);
    y = __fadd_rn(y, 1.0f);
    const int n = (int)fx;
    const float sc = __int_as_float((n + 127) << 23);
    return __fmul_rn(y, sc);
}

// ---------------------------------------------------------------------------
// XLA-CPU JIT-emitted tanh f32 (llvm_ir_runtime VF32Tanh): clamp +/-9.0,
// no tiny-x passthrough, FMA Horner rational P/Q, IEEE divide.
// ---------------------------------------------------------------------------
__device__ __forceinline__ float tanh_vsl(float x) {
    const float xc = fminf(fmaxf(x, -9.0f), 9.0f);
    const float x2 = __fmul_rn(xc, xc);
    float p = -2.76076847742355e-16f;
    p = fmaf(p, x2, 2.00018790482477e-13f);
    p = fmaf(p, x2, -8.60467152213735e-11f);
    p = fmaf(p, x2, 5.12229709037114e-08f);
    p = fmaf(p, x2, 1.48572235717979e-05f);
    p = fmaf(p, x2, 6.37261928875436e-04f);
    p = fmaf(p, x2, 4.89352455891786e-03f);
    p = __fmul_rn(p, xc);
    float q = 1.19825839466702e-06f;
    q = fmaf(q, x2, 1.18534705686654e-04f);
    q = fmaf(q, x2, 2.26843463243900e-03f);
    q = fmaf(q, x2, 4.89352518554385e-03f);
    return __fdiv_rn(p, q);
}

// XLA LogisticExpander (modern): 1 / (1 + exp(-x))
__device__ __forceinline__ float sig_vsl(float x) {
    const float ef = exp_vsl(-x);
    return __fdiv_rn(1.0f, __fadd_rn(1.0f, ef));
}

// ---------------------------------------------------------------------------
// Prep: wi -> fq fp32, wh -> packed int8 transposed, biases quantized
// separately, zero recurrent state.
// ---------------------------------------------------------------------------
__global__ void qlstm_prep(const float* __restrict__ wih, const float* __restrict__ whh,
                           const float* __restrict__ bih, const float* __restrict__ bhh,
                           float* __restrict__ wiq, int* __restrict__ whqT,
                           float* __restrict__ biq, float* __restrict__ bhq,
                           float* __restrict__ c_state, int* __restrict__ hq_state) {
    const int idx = blockIdx.x * 256 + threadIdx.x;
    if (idx < G4 * IN_D) wiq[idx] = fq4(wih[idx]);
    if (idx < (HID / 4) * G4) {
        const int d = idx >> 10;
        const int j = idx & 1023;
        int pack = 0;
#pragma unroll
        for (int c = 0; c < 4; ++c) {
            const int k = d * 4 + c;
            float q = fminf(fmaxf(rintf(whh[j * HID + k] * 16.0f), -128.0f), 127.0f);
            int qi = (int)q;
            pack |= (qi & 0xff) << (8 * c);
        }
        whqT[idx] = pack;
    }
    if (idx < G4) { biq[idx] = fq4(bih[idx]); bhq[idx] = fq4(bhh[idx]); }
    if (idx < BATCH * HID) c_state[idx] = 0.0f;
    if (idx < BATCH * (HID / 4)) hq_state[idx] = 0;
}

// ---------------------------------------------------------------------------
// Gx[m,n] = sum_k X[m,k]*Wq[n,k] + biq[n], UNFUSED accumulation:
// acc = add(acc, mul(a,b)) ascending k — Eigen gebp compiled AVX-only
// (jaxlib's prebuilt __xla_cpu_runtime_EigenMatMulF32: pmadd = padd(pmul))
// — separate rounding of every product, single accumulator per C element.
// ---------------------------------------------------------------------------
#define GPAD 132
__global__ __launch_bounds__(256, 1) void qlstm_gx(
    const float* __restrict__ X, const float* __restrict__ Wq,
    const float* __restrict__ biq, float* __restrict__ Gx, int Mc) {
    __shared__ float Xs[IN_D][GPAD];
    __shared__ float Ws[IN_D][GPAD];
    const int t  = threadIdx.x;
    const int m0 = blockIdx.x * 128;
    const int n0 = blockIdx.y * 128;

#pragma unroll
    for (int i = 0; i < 16; ++i) {
        const int flat = i * 256 + t;
        const int m  = flat >> 5;
        const int k4 = flat & 31;
        float4 v = make_float4(0.f, 0.f, 0.f, 0.f);
        if (m0 + m < Mc) v = *(const float4*)(X + (size_t)(m0 + m) * IN_D + k4 * 4);
        Xs[k4 * 4 + 0][m] = v.x; Xs[k4 * 4 + 1][m] = v.y;
        Xs[k4 * 4 + 2][m] = v.z; Xs[k4 * 4 + 3][m] = v.w;
        float4 w = *(const float4*)(Wq + (size_t)(n0 + m) * IN_D + k4 * 4);
        Ws[k4 * 4 + 0][m] = w.x; Ws[k4 * 4 + 1][m] = w.y;
        Ws[k4 * 4 + 2][m] = w.z; Ws[k4 * 4 + 3][m] = w.w;
    }
    __syncthreads();

    const int tx = t & 15, ty = t >> 4;
    float acc[8][8];
#pragma unroll
    for (int i = 0; i < 8; ++i)
#pragma unroll
        for (int j = 0; j < 8; ++j) acc[i][j] = 0.0f;

#pragma unroll 4
    for (int k = 0; k < IN_D; ++k) {
        float4 a0 = *(const float4*)&Xs[k][ty * 8];
        float4 a1 = *(const float4*)&Xs[k][ty * 8 + 4];
        float4 b0 = *(const float4*)&Ws[k][tx * 8];
        float4 b1 = *(const float4*)&Ws[k][tx * 8 + 4];
        const float a[8]  = {a0.x, a0.y, a0.z, a0.w, a1.x, a1.y, a1.z, a1.w};
        const float bb[8] = {b0.x, b0.y, b0.z, b0.w, b1.x, b1.y, b1.z, b1.w};
#pragma unroll
        for (int i = 0; i < 8; ++i)
#pragma unroll
            for (int j = 0; j < 8; ++j)
                acc[i][j] = __fadd_rn(acc[i][j], __fmul_rn(a[i], bb[j]));   // UNFUSED
    }

    float4 bv0 = *(const float4*)(biq + n0 + tx * 8);
    float4 bv1 = *(const float4*)(biq + n0 + tx * 8 + 4);
    const float bb[8] = {bv0.x, bv0.y, bv0.z, bv0.w, bv1.x, bv1.y, bv1.z, bv1.w};
#pragma unroll
    for (int i = 0; i < 8; ++i) {
        const int m = m0 + ty * 8 + i;
        if (m < Mc) {
            float o[8];
#pragma unroll
            for (int j = 0; j < 8; ++j) o[j] = __fadd_rn(acc[i][j], bb[j]);
            *(float4*)(Gx + (size_t)m * G4 + n0 + tx * 8)     = make_float4(o[0], o[1], o[2], o[3]);
            *(float4*)(Gx + (size_t)m * G4 + n0 + tx * 8 + 4) = make_float4(o[4], o[5], o[6], o[7]);
        }
    }
}

// ---------------------------------------------------------------------------
// Scan, f32 state, XLA-CPU-JIT op-for-op:
//   gates = ((x@wiT + bi) + hh) + bh     [hh exact int8 dot]
//   i,f,o = 1/(1+exp_vsl(-g))           [LogisticExpander + JIT exp]
//   g, tanh(c1) = tanh_vsl              [JIT tanh, clamp ±9]
//   c1 = fma(f, cq, i*g)                [contract-on elementwise emission]
// ---------------------------------------------------------------------------
__global__ __launch_bounds__(512, 2) void qlstm_scan(
    const float* __restrict__ Gx, const int* __restrict__ whqT,
    const float* __restrict__ bhq,
    float* __restrict__ out, float* __restrict__ c_state, int* __restrict__ hq_state,
    float* __restrict__ hn, float* __restrict__ cn, int s0, int CHc) {
    const int b = blockIdx.x;
    const int t = threadIdx.x;

    __shared__ __align__(16) int hq[2][64];
    __shared__ float gl[G4];
    __shared__ float gv_s[HID], ov_s[HID];

    int w0[64], w1[64];
#pragma unroll
    for (int d = 0; d < 64; ++d) {
        w0[d] = whqT[d * G4 + t];
        w1[d] = whqT[d * G4 + t + 512];
    }
    const float bh0 = bhq[t];
    const float bh1 = bhq[t + 512];

    float creg = 0.0f;
    if (t < HID) creg = c_state[b * HID + t];
    if (t < 64)  hq[0][t] = hq_state[b * 64 + t];
    __syncthreads();

    float gx0 = Gx[(size_t)b * G4 + t];
    float gx1 = Gx[(size_t)b * G4 + t + 512];

    for (int sl = 0; sl < CHc; ++sl) {
        const int p = sl & 1;
        float nx0 = 0.0f, nx1 = 0.0f;
        if (sl + 1 < CHc) {
            const size_t base = (size_t)((sl + 1) * BATCH + b) * G4;
            nx0 = Gx[base + t];
            nx1 = Gx[base + t + 512];
        }

        int acc0 = 0, acc1 = 0;
#pragma unroll
        for (int dd = 0; dd < 16; ++dd) {
            const int4 hv = ((const int4*)hq[p])[dd];
            acc0 = dot4i8(w0[dd * 4 + 0], hv.x, acc0);
            acc0 = dot4i8(w0[dd * 4 + 1], hv.y, acc0);
            acc0 = dot4i8(w0[dd * 4 + 2], hv.z, acc0);
            acc0 = dot4i8(w0[dd * 4 + 3], hv.w, acc0);
            acc1 = dot4i8(w1[dd * 4 + 0], hv.x, acc1);
            acc1 = dot4i8(w1[dd * 4 + 1], hv.y, acc1);
            acc1 = dot4i8(w1[dd * 4 + 2], hv.z, acc1);
            acc1 = dot4i8(w1[dd * 4 + 3], hv.w, acc1);
        }
        const float hh0 = (float)acc0 * 0.00390625f;   // exact multiple of 2^-8
        const float hh1 = (float)acc1 * 0.00390625f;
        gl[t]       = __fadd_rn(__fadd_rn(gx0, hh0), bh0);
        gl[t + 512] = __fadd_rn(__fadd_rn(gx1, hh1), bh1);
        __syncthreads();

        float iv = 0.0f, fv = 0.0f;
        if (t < HID) {
            iv = sig_vsl(gl[t]);
            fv = sig_vsl(gl[t + HID]);
        } else {
            const int j = t - HID;
            gv_s[j] = tanh_vsl(gl[j + 2 * HID]);
            ov_s[j] = sig_vsl(gl[j + 3 * HID]);
        }
        __syncthreads();

        if (t < HID) {
            const float cq = fminf(fmaxf(rintf(__fmul_rn(creg, 16.0f)), -128.0f), 127.0f) * 0.0625f;
            const float c1 = fmaf(fv, cq, __fmul_rn(iv, gv_s[t]));   // contracted
            const float h1 = __fmul_rn(ov_s[t], tanh_vsl(c1));
            creg = c1;
            out[(size_t)((s0 + sl) * BATCH + b) * HID + t] = h1;
            const int hb = (int)fminf(fmaxf(rintf(__fmul_rn(h1, 16.0f)), -128.0f), 127.0f);
            ((signed char*)hq[p ^ 1])[t] = (signed char)hb;
            if (s0 + sl == S_LEN - 1) {
                hn[b * HID + t] = h1;
                cn[b * HID + t] = c1;
            }
        }
        __syncthreads();
        gx0 = nx0; gx1 = nx1;
    }

    if (t < 64)  hq_state[b * 64 + t] = hq[CHc & 1][t];
    if (t < HID) c_state[b * HID + t] = creg;
}

// ---------------------------------------------------------------------------
// Host side
// ---------------------------------------------------------------------------
extern "C" void kernel_launch(void* const* d_in, const int* in_sizes, int n_in,
                              void* d_out, int out_size, void* d_ws, size_t ws_size,
                              hipStream_t stream) {
    (void)in_sizes; (void)n_in; (void)out_size;
    const float* x   = (const float*)d_in[0];
    const float* wih = (const float*)d_in[1];
    const float* whh = (const float*)d_in[2];
    const float* bih = (const float*)d_in[3];
    const float* bhh = (const float*)d_in[4];

    float* out = (float*)d_out;
    float* hn  = out + (size_t)S_LEN * BATCH * HID;
    float* cn  = hn + (size_t)BATCH * HID;

    char* ws = (char*)d_ws;
    const size_t off_wiq  = 0;
    const size_t off_whqT = off_wiq  + 524288;
    const size_t off_biq  = off_whqT + 262144;
    const size_t off_bhq  = off_biq  + 4096;
    const size_t off_c    = off_bhq  + 4096;
    const size_t off_hq   = off_c    + 65536;
    const size_t off_gx   = off_hq   + 16384;

    float* wiq     = (float*)(ws + off_wiq);
    int*   whqT    = (int*)  (ws + off_whqT);
    float* biq     = (float*)(ws + off_biq);
    float* bhq     = (float*)(ws + off_bhq);
    float* c_state = (float*)(ws + off_c);
    int*   hq_st   = (int*)  (ws + off_hq);
    float* gx      = (float*)(ws + off_gx);

    const size_t per_step = (size_t)BATCH * G4 * 4;
    size_t avail = (ws_size > off_gx) ? (ws_size - off_gx) : 0;
    int CH = (int)(avail / per_step);
    if (CH > S_LEN) CH = S_LEN;
    if (CH < 1) CH = 1;

    qlstm_prep<<<512, 256, 0, stream>>>(wih, whh, bih, bhh, wiq, whqT, biq, bhq, c_state, hq_st);

    for (int s0 = 0; s0 < S_LEN; s0 += CH) {
        const int CHc = (S_LEN - s0 < CH) ? (S_LEN - s0) : CH;
        const int Mc  = CHc * BATCH;
        dim3 grid((Mc + 127) / 128, G4 / 128);
        qlstm_gx<<<grid, 256, 0, stream>>>(x + (size_t)s0 * BATCH * IN_D, wiq, biq, gx, Mc);
        qlstm_scan<<<64, 512, 0, stream>>>(gx, whqT, bhq, out, c_state, hq_st, hn, cn, s0, CHc);
    }
}

// Round 15
// 2980.323 us; speedup vs baseline: 1.0289x; 1.0289x over previous
//
#include <hip/hip_runtime.h>
#include <math.h>

#define S_LEN 2048
#define BATCH 64
#define IN_D  128
#define HID   256
#define G4    1024   // 4*HID

#if defined(__has_builtin)
# if __has_builtin(__builtin_amdgcn_sdot4)
#  define USE_SDOT4 1
# endif
#endif

__device__ __forceinline__ int dot4i8(int a, int b, int c) {
#ifdef USE_SDOT4
    return __builtin_amdgcn_sdot4(a, b, c, false);
#else
    int r = c;
    r += ((a << 24) >> 24) * ((b << 24) >> 24);
    r += ((a << 16) >> 24) * ((b << 16) >> 24);
    r += ((a <<  8) >> 24) * ((b <<  8) >> 24);
    r += ( a        >> 24) * ( b        >> 24);
    return r;
#endif
}

// fake_quant value: clip(round_half_even(x*16), -128, 127)/16 — exact f32 ops
__device__ __forceinline__ float fq4(float x) {
    return fminf(fmaxf(rintf(x * 16.0f), -128.0f), 127.0f) * 0.0625f;
}

// ---------------------------------------------------------------------------
// XLA-CPU JIT exp f32 (VF32Exp, FMA host, contract ON) — bit-frozen from r14.
// ---------------------------------------------------------------------------
__device__ __forceinline__ float exp_vsl(float x) {
    const float xc = fminf(fmaxf(x, -88.3762626647949f), 88.3762626647950f);
    const float fx = floorf(fmaf(xc, 1.44269504088896341f, 0.5f));
    float r = fmaf(-fx, 0.693359375f, xc);
    r = fmaf(fx, 2.12194440e-4f, r);
    const float z = __fmul_rn(r, r);
    float y = fmaf(r, 1.9875691500e-4f, 1.3981999507e-3f);
    y = fmaf(y, r, 8.3334519073e-3f);
    y = fmaf(y, r, 4.1665795894e-2f);
    y = fmaf(y, r, 1.6666665459e-1f);
    y = fmaf(y, r, 5.0000001201e-1f);
    y = fmaf(y, z, r);
    y = __fadd_rn(y, 1.0f);
    const int n = (int)fx;
    const float sc = __int_as_float((n + 127) << 23);
    return __fmul_rn(y, sc);
}

// ---------------------------------------------------------------------------
// XLA-CPU JIT tanh f32 (VF32Tanh): clamp ±9, FMA Horner — bit-frozen from r14.
// ---------------------------------------------------------------------------
__device__ __forceinline__ float tanh_vsl(float x) {
    const float xc = fminf(fmaxf(x, -9.0f), 9.0f);
    const float x2 = __fmul_rn(xc, xc);
    float p = -2.76076847742355e-16f;
    p = fmaf(p, x2, 2.00018790482477e-13f);
    p = fmaf(p, x2, -8.60467152213735e-11f);
    p = fmaf(p, x2, 5.12229709037114e-08f);
    p = fmaf(p, x2, 1.48572235717979e-05f);
    p = fmaf(p, x2, 6.37261928875436e-04f);
    p = fmaf(p, x2, 4.89352455891786e-03f);
    p = __fmul_rn(p, xc);
    float q = 1.19825839466702e-06f;
    q = fmaf(q, x2, 1.18534705686654e-04f);
    q = fmaf(q, x2, 2.26843463243900e-03f);
    q = fmaf(q, x2, 4.89352518554385e-03f);
    return __fdiv_rn(p, q);
}

// XLA LogisticExpander: 1 / (1 + exp(-x)) — bit-frozen.
__device__ __forceinline__ float sig_vsl(float x) {
    const float ef = exp_vsl(-x);
    return __fdiv_rn(1.0f, __fadd_rn(1.0f, ef));
}

// ---------------------------------------------------------------------------
// Prep (unchanged from r14)
// ---------------------------------------------------------------------------
__global__ void qlstm_prep(const float* __restrict__ wih, const float* __restrict__ whh,
                           const float* __restrict__ bih, const float* __restrict__ bhh,
                           float* __restrict__ wiq, int* __restrict__ whqT,
                           float* __restrict__ biq, float* __restrict__ bhq,
                           float* __restrict__ c_state, int* __restrict__ hq_state) {
    const int idx = blockIdx.x * 256 + threadIdx.x;
    if (idx < G4 * IN_D) wiq[idx] = fq4(wih[idx]);
    if (idx < (HID / 4) * G4) {
        const int d = idx >> 10;
        const int j = idx & 1023;
        int pack = 0;
#pragma unroll
        for (int c = 0; c < 4; ++c) {
            const int k = d * 4 + c;
            float q = fminf(fmaxf(rintf(whh[j * HID + k] * 16.0f), -128.0f), 127.0f);
            int qi = (int)q;
            pack |= (qi & 0xff) << (8 * c);
        }
        whqT[idx] = pack;
    }
    if (idx < G4) { biq[idx] = fq4(bih[idx]); bhq[idx] = fq4(bhh[idx]); }
    if (idx < BATCH * HID) c_state[idx] = 0.0f;
    if (idx < BATCH * (HID / 4)) hq_state[idx] = 0;
}

// ---------------------------------------------------------------------------
// GEMM: UNFUSED acc = add(acc, mul(a,b)) ascending k (bit-frozen from r14).
// ---------------------------------------------------------------------------
#define GPAD 132
__global__ __launch_bounds__(256, 1) void qlstm_gx(
    const float* __restrict__ X, const float* __restrict__ Wq,
    const float* __restrict__ biq, float* __restrict__ Gx, int Mc) {
    __shared__ float Xs[IN_D][GPAD];
    __shared__ float Ws[IN_D][GPAD];
    const int t  = threadIdx.x;
    const int m0 = blockIdx.x * 128;
    const int n0 = blockIdx.y * 128;

#pragma unroll
    for (int i = 0; i < 16; ++i) {
        const int flat = i * 256 + t;
        const int m  = flat >> 5;
        const int k4 = flat & 31;
        float4 v = make_float4(0.f, 0.f, 0.f, 0.f);
        if (m0 + m < Mc) v = *(const float4*)(X + (size_t)(m0 + m) * IN_D + k4 * 4);
        Xs[k4 * 4 + 0][m] = v.x; Xs[k4 * 4 + 1][m] = v.y;
        Xs[k4 * 4 + 2][m] = v.z; Xs[k4 * 4 + 3][m] = v.w;
        float4 w = *(const float4*)(Wq + (size_t)(n0 + m) * IN_D + k4 * 4);
        Ws[k4 * 4 + 0][m] = w.x; Ws[k4 * 4 + 1][m] = w.y;
        Ws[k4 * 4 + 2][m] = w.z; Ws[k4 * 4 + 3][m] = w.w;
    }
    __syncthreads();

    const int tx = t & 15, ty = t >> 4;
    float acc[8][8];
#pragma unroll
    for (int i = 0; i < 8; ++i)
#pragma unroll
        for (int j = 0; j < 8; ++j) acc[i][j] = 0.0f;

#pragma unroll 4
    for (int k = 0; k < IN_D; ++k) {
        float4 a0 = *(const float4*)&Xs[k][ty * 8];
        float4 a1 = *(const float4*)&Xs[k][ty * 8 + 4];
        float4 b0 = *(const float4*)&Ws[k][tx * 8];
        float4 b1 = *(const float4*)&Ws[k][tx * 8 + 4];
        const float a[8]  = {a0.x, a0.y, a0.z, a0.w, a1.x, a1.y, a1.z, a1.w};
        const float bb[8] = {b0.x, b0.y, b0.z, b0.w, b1.x, b1.y, b1.z, b1.w};
#pragma unroll
        for (int i = 0; i < 8; ++i)
#pragma unroll
            for (int j = 0; j < 8; ++j)
                acc[i][j] = __fadd_rn(acc[i][j], __fmul_rn(a[i], bb[j]));   // UNFUSED
    }

    float4 bv0 = *(const float4*)(biq + n0 + tx * 8);
    float4 bv1 = *(const float4*)(biq + n0 + tx * 8 + 4);
    const float bb[8] = {bv0.x, bv0.y, bv0.z, bv0.w, bv1.x, bv1.y, bv1.z, bv1.w};
#pragma unroll
    for (int i = 0; i < 8; ++i) {
        const int m = m0 + ty * 8 + i;
        if (m < Mc) {
            float o[8];
#pragma unroll
            for (int j = 0; j < 8; ++j) o[j] = __fadd_rn(acc[i][j], bb[j]);
            *(float4*)(Gx + (size_t)m * G4 + n0 + tx * 8)     = make_float4(o[0], o[1], o[2], o[3]);
            *(float4*)(Gx + (size_t)m * G4 + n0 + tx * 8 + 4) = make_float4(o[4], o[5], o[6], o[7]);
        }
    }
}

// ---------------------------------------------------------------------------
// Scan — arithmetic bit-identical to the passing r14 kernel; restructured
// data movement: no gl[] round-trip (gates consumed from registers), {f,o}
// exchanged as one float2, 2 barriers/step instead of 3, int8 dot split into
// 4 independent accumulator chains (integer reassociation exact).
// Thread t<256 owns rows (i_t, g_t); thread t>=256 owns (f_{t-256}, o_{t-256}).
// ---------------------------------------------------------------------------
__global__ __launch_bounds__(512, 2) void qlstm_scan(
    const float* __restrict__ Gx, const int* __restrict__ whqT,
    const float* __restrict__ bhq,
    float* __restrict__ out, float* __restrict__ c_state, int* __restrict__ hq_state,
    float* __restrict__ hn, float* __restrict__ cn, int s0, int CHc) {
    const int b = blockIdx.x;
    const int t = threadIdx.x;

    __shared__ __align__(16) int hq[2][64];   // packed int8 fq(h)*16, double buffered
    __shared__ float2 fo_s[HID];              // {f, o} handoff high->low lanes

    int w0[64], w1[64];
#pragma unroll
    for (int d = 0; d < 64; ++d) {
        w0[d] = whqT[d * G4 + t];
        w1[d] = whqT[d * G4 + t + 512];
    }
    const float bh0 = bhq[t];
    const float bh1 = bhq[t + 512];

    float creg = 0.0f;
    if (t < HID) creg = c_state[b * HID + t];
    if (t < 64)  hq[0][t] = hq_state[b * 64 + t];
    __syncthreads();

    float gx0 = Gx[(size_t)b * G4 + t];
    float gx1 = Gx[(size_t)b * G4 + t + 512];

    for (int sl = 0; sl < CHc; ++sl) {
        const int p = sl & 1;
        float nx0 = 0.0f, nx1 = 0.0f;
        if (sl + 1 < CHc) {
            const size_t base = (size_t)((sl + 1) * BATCH + b) * G4;
            nx0 = Gx[base + t];
            nx1 = Gx[base + t + 512];
        }

        // hh matvec: 4 independent chains per row (integer-exact reassociation)
        int c0a[4] = {0, 0, 0, 0};
        int c1a[4] = {0, 0, 0, 0};
#pragma unroll
        for (int j = 0; j < 4; ++j) {
#pragma unroll
            for (int d = 0; d < 4; ++d) {
                const int4 hv = ((const int4*)hq[p])[j * 4 + d];   // broadcast read
                const int base = (j * 4 + d) * 4;
                c0a[j] = dot4i8(w0[base + 0], hv.x, c0a[j]);
                c0a[j] = dot4i8(w0[base + 1], hv.y, c0a[j]);
                c0a[j] = dot4i8(w0[base + 2], hv.z, c0a[j]);
                c0a[j] = dot4i8(w0[base + 3], hv.w, c0a[j]);
                c1a[j] = dot4i8(w1[base + 0], hv.x, c1a[j]);
                c1a[j] = dot4i8(w1[base + 1], hv.y, c1a[j]);
                c1a[j] = dot4i8(w1[base + 2], hv.z, c1a[j]);
                c1a[j] = dot4i8(w1[base + 3], hv.w, c1a[j]);
            }
        }
        const int acc0 = (c0a[0] + c0a[1]) + (c0a[2] + c0a[3]);
        const int acc1 = (c1a[0] + c1a[1]) + (c1a[2] + c1a[3]);

        const float hh0 = (float)acc0 * 0.00390625f;   // exact multiple of 2^-8
        const float hh1 = (float)acc1 * 0.00390625f;
        const float gate0 = __fadd_rn(__fadd_rn(gx0, hh0), bh0);   // rows t
        const float gate1 = __fadd_rn(__fadd_rn(gx1, hh1), bh1);   // rows t+512

        float iv = 0.0f, gv = 0.0f;
        if (t < HID) {                       // rows t = i_t, t+512 = g_t
            iv = sig_vsl(gate0);
            gv = tanh_vsl(gate1);
        } else {                             // rows t = f_j, t+512 = o_j (j=t-256)
            const float fv = sig_vsl(gate0);
            const float ov = sig_vsl(gate1);
            fo_s[t - HID] = make_float2(fv, ov);
        }
        __syncthreads();

        if (t < HID) {
            const float2 fo = fo_s[t];
            const float cq = fminf(fmaxf(rintf(__fmul_rn(creg, 16.0f)), -128.0f), 127.0f) * 0.0625f;
            const float c1 = fmaf(fo.x, cq, __fmul_rn(iv, gv));   // contracted (r14)
            const float h1 = __fmul_rn(fo.y, tanh_vsl(c1));
            creg = c1;
            out[(size_t)((s0 + sl) * BATCH + b) * HID + t] = h1;
            const int hb = (int)fminf(fmaxf(rintf(__fmul_rn(h1, 16.0f)), -128.0f), 127.0f);
            ((signed char*)hq[p ^ 1])[t] = (signed char)hb;
            if (s0 + sl == S_LEN - 1) {
                hn[b * HID + t] = h1;
                cn[b * HID + t] = c1;
            }
        }
        __syncthreads();
        gx0 = nx0; gx1 = nx1;
    }

    if (t < 64)  hq_state[b * 64 + t] = hq[CHc & 1][t];
    if (t < HID) c_state[b * HID + t] = creg;
}

// ---------------------------------------------------------------------------
// Host side (unchanged)
// ---------------------------------------------------------------------------
extern "C" void kernel_launch(void* const* d_in, const int* in_sizes, int n_in,
                              void* d_out, int out_size, void* d_ws, size_t ws_size,
                              hipStream_t stream) {
    (void)in_sizes; (void)n_in; (void)out_size;
    const float* x   = (const float*)d_in[0];
    const float* wih = (const float*)d_in[1];
    const float* whh = (const float*)d_in[2];
    const float* bih = (const float*)d_in[3];
    const float* bhh = (const float*)d_in[4];

    float* out = (float*)d_out;
    float* hn  = out + (size_t)S_LEN * BATCH * HID;
    float* cn  = hn + (size_t)BATCH * HID;

    char* ws = (char*)d_ws;
    const size_t off_wiq  = 0;
    const size_t off_whqT = off_wiq  + 524288;
    const size_t off_biq  = off_whqT + 262144;
    const size_t off_bhq  = off_biq  + 4096;
    const size_t off_c    = off_bhq  + 4096;
    const size_t off_hq   = off_c    + 65536;
    const size_t off_gx   = off_hq   + 16384;

    float* wiq     = (float*)(ws + off_wiq);
    int*   whqT    = (int*)  (ws + off_whqT);
    float* biq     = (float*)(ws + off_biq);
    float* bhq     = (float*)(ws + off_bhq);
    float* c_state = (float*)(ws + off_c);
    int*   hq_st   = (int*)  (ws + off_hq);
    float* gx      = (float*)(ws + off_gx);

    const size_t per_step = (size_t)BATCH * G4 * 4;
    size_t avail = (ws_size > off_gx) ? (ws_size - off_gx) : 0;
    int CH = (int)(avail / per_step);
    if (CH > S_LEN) CH = S_LEN;
    if (CH < 1) CH = 1;

    qlstm_prep<<<512, 256, 0, stream>>>(wih, whh, bih, bhh, wiq, whqT, biq, bhq, c_state, hq_st);

    for (int s0 = 0; s0 < S_LEN; s0 += CH) {
        const int CHc = (S_LEN - s0 < CH) ? (S_LEN - s0) : CH;
        const int Mc  = CHc * BATCH;
        dim3 grid((Mc + 127) / 128, G4 / 128);
        qlstm_gx<<<grid, 256, 0, stream>>>(x + (size_t)s0 * BATCH * IN_D, wiq, biq, gx, Mc);
        qlstm_scan<<<64, 512, 0, stream>>>(gx, whqT, bhq, out, c_state, hq_st, hn, cn, s0, CHc);
    }
}